// Round 7
// baseline (1920.474 us; speedup 1.0000x reference)
//
#include <hip/hip_runtime.h>

// MsCorrBlock: B=8 T=8 C=256 PL=64 CR=16 H=W=56 HW=3136 NT=64 PS=7 KK=49
// Output dtype: FLOAT32 (205,520,896 B). BNI = 1/sqrt(1+1e-5).

#define MSC_BNI 0.9999950000374997f

static __device__ __forceinline__ float b2f(unsigned short h) {
  return __uint_as_float(((unsigned int)h) << 16);
}
static __device__ __forceinline__ unsigned short f2b(float f) {
  unsigned int u = __float_as_uint(f);
  u = u + 0x7FFFu + ((u >> 16) & 1u);   // round to nearest even
  return (unsigned short)(u >> 16);
}

// K1: per-channel temporal conv (K=1/3/5/7 by channel quarter), x fp32 -> A bf16.
__global__ __launch_bounds__(256) void k1_tconv(
    const float* x, unsigned short* A,
    const float* w1, const float* w3, const float* w5, const float* w7) {
  int i = blockIdx.x * 256 + threadIdx.x;       // over 8*256*3136 = 6,422,528
  if (i >= 6422528) return;
  int hw = i % 3136;
  int bc = i / 3136;
  int c = bc & 255;
  int b = bc >> 8;
  int q = c >> 6, cc = c & 63;
  float wf[7];
#pragma unroll
  for (int k = 0; k < 7; k++) wf[k] = 0.f;
  if (q == 0) { wf[3] = w1[cc]; }
  else if (q == 1) { wf[2] = w3[cc*3]; wf[3] = w3[cc*3+1]; wf[4] = w3[cc*3+2]; }
  else if (q == 2) { wf[1] = w5[cc*5]; wf[2] = w5[cc*5+1]; wf[3] = w5[cc*5+2]; wf[4] = w5[cc*5+3]; wf[5] = w5[cc*5+4]; }
  else { wf[0] = w7[cc*7]; wf[1] = w7[cc*7+1]; wf[2] = w7[cc*7+2]; wf[3] = w7[cc*7+3]; wf[4] = w7[cc*7+4]; wf[5] = w7[cc*7+5]; wf[6] = w7[cc*7+6]; }

  int base = (b * 8 * 256 + c) * 3136 + hw;     // t=0 element
  int tstr = 256 * 3136;
  float xv[8];
#pragma unroll
  for (int t = 0; t < 8; t++) xv[t] = x[base + t * tstr];
#pragma unroll
  for (int t = 0; t < 8; t++) {
    float a = 0.f;
#pragma unroll
    for (int d = -3; d <= 3; d++) {
      int ts = t + d;
      if (ts >= 0 && ts < 8) a = fmaf(wf[d + 3], xv[ts], a);
    }
    A[base + t * tstr] = f2b(a);
  }
}

// K2: 1x1 conv 256->64 + BN + ReLU.  A bf16 -> R2 fp32.
// Block = (n, 64-wide hw tile). Thread = (hw, o-chunk of 16). LDS 32 KB.
__global__ __launch_bounds__(256) void k2_conv1(
    const unsigned short* A, float* R2,
    const float* w, const float* g, const float* bb) {
  __shared__ unsigned short As[256][64];        // 32 KB
  int n = blockIdx.x / 49;
  int hw0 = (blockIdx.x % 49) * 64;
  const unsigned short* Ab = A + n * 256 * 3136 + hw0;
  for (int idx = threadIdx.x; idx < 16384; idx += 256) {
    int r = idx >> 6, cl = idx & 63;
    As[r][cl] = Ab[r * 3136 + cl];
  }
  __syncthreads();
  int hw = threadIdx.x & 63;
  int oc = threadIdx.x >> 6;                    // 0..3 -> o = oc*16 + j
  const float* wb = w + oc * 16 * 256;          // wave-uniform rows
  float acc[16];
#pragma unroll
  for (int j = 0; j < 16; j++) acc[j] = 0.f;
  for (int c = 0; c < 256; c++) {
    float a = b2f(As[c][hw]);
#pragma unroll
    for (int j = 0; j < 16; j++) acc[j] = fmaf(wb[j * 256 + c], a, acc[j]);
  }
  int obase = (n * 64 + oc * 16) * 3136 + hw0 + hw;
#pragma unroll
  for (int j = 0; j < 16; j++) {
    int o = oc * 16 + j;
    R2[obase + j * 3136] = fmaxf(fmaf(acc[j], g[o] * MSC_BNI, bb[o]), 0.f);
  }
}

// K3: 1x1 conv 64->16 + BN + ReLU.  R2 -> Y.  LDS 16 KB.
__global__ __launch_bounds__(256) void k3_conv21(
    const float* R2, float* Y,
    const float* w, const float* g, const float* bb) {
  __shared__ float As[64][64];                  // 16 KB
  int n = blockIdx.x / 49;
  int hw0 = (blockIdx.x % 49) * 64;
  const float* Rb = R2 + n * 64 * 3136 + hw0;
  for (int idx = threadIdx.x; idx < 4096; idx += 256) {
    int r = idx >> 6, cl = idx & 63;
    As[r][cl] = Rb[r * 3136 + cl];
  }
  __syncthreads();
  int hw = threadIdx.x & 63;
  int oc = threadIdx.x >> 6;                    // 0..3 -> o = oc*4 + j
  const float* wb = w + oc * 4 * 64;
  float acc[4];
#pragma unroll
  for (int j = 0; j < 4; j++) acc[j] = 0.f;
  for (int c = 0; c < 64; c++) {
    float a = As[c][hw];
#pragma unroll
    for (int j = 0; j < 4; j++) acc[j] = fmaf(wb[j * 64 + c], a, acc[j]);
  }
  int obase = (n * 16 + oc * 4) * 3136 + hw0 + hw;
#pragma unroll
  for (int j = 0; j < 4; j++) {
    int o = oc * 4 + j;
    Y[obase + j * 3136] = fmaxf(fmaf(acc[j], g[o] * MSC_BNI, bb[o]), 0.f);
  }
}

// K4: 7x7-displacement correlation (vs t+1 clamped frame) /16 + BN + ReLU.
// Y (NT,16,HW) -> CO (NT,49,HW).  LDS ~38.8 KB.
__global__ __launch_bounds__(256) void k4_corr(
    const float* Y, float* CO, const float* g, const float* bb) {
  __shared__ float sb[10][16][62];              // rows h0-3..h0+6, ch, cols -3..58
  int n = blockIdx.x / 14;
  int h0 = (blockIdx.x % 14) * 4;
  int t = n & 7;
  int n2 = (t < 7) ? n + 1 : n;
  const float* Yb = Y + n2 * 16 * 3136;
  for (int idx = threadIdx.x; idx < 9920; idx += 256) {
    int r = idx / 992;
    int rem = idx - r * 992;
    int ch = rem / 62;
    int cl = rem - ch * 62;
    int gr = h0 - 3 + r, gc = cl - 3;
    float v = 0.f;
    if (gr >= 0 && gr < 56 && gc >= 0 && gc < 56)
      v = Yb[ch * 3136 + gr * 56 + gc];
    sb[r][ch][cl] = v;
  }
  __syncthreads();
  int pos = threadIdx.x;
  if (pos < 224) {
    int hl = pos / 56, wcol = pos - (pos / 56) * 56;
    float a[16];
    const float* Ya = Y + n * 16 * 3136 + (h0 + hl) * 56 + wcol;
#pragma unroll
    for (int c = 0; c < 16; c++) a[c] = Ya[c * 3136];
    float* Cp = CO + n * 49 * 3136 + (h0 + hl) * 56 + wcol;
    for (int di = 0; di < 7; di++) {
      for (int dj = 0; dj < 7; dj++) {
        float s = 0.f;
#pragma unroll
        for (int c = 0; c < 16; c++) s = fmaf(a[c], sb[hl + di][c][wcol + dj], s);
        int k = di * 7 + dj;
        float v = fmaf(s * 0.0625f, g[k] * MSC_BNI, bb[k]);
        Cp[k * 3136] = fmaxf(v, 0.f);
      }
    }
  }
}

// K5: 1x1 conv 49->64 + BN + res2-add + ReLU -> O2 fp32.  LDS ~12.5 KB.
__global__ __launch_bounds__(256) void k5_conv22(
    const float* CO, const float* R2, float* O2,
    const float* w, const float* g, const float* bb) {
  __shared__ float As[49][64];                  // 12.25 KB
  int n = blockIdx.x / 49;
  int hw0 = (blockIdx.x % 49) * 64;
  const float* Cb = CO + n * 49 * 3136 + hw0;
  for (int idx = threadIdx.x; idx < 3136; idx += 256) {
    int r = idx >> 6, cl = idx & 63;
    As[r][cl] = Cb[r * 3136 + cl];
  }
  __syncthreads();
  int hw = threadIdx.x & 63;
  int oc = threadIdx.x >> 6;                    // 0..3 -> o = oc*16 + j
  const float* wb = w + oc * 16 * 49;
  float acc[16];
#pragma unroll
  for (int j = 0; j < 16; j++) acc[j] = 0.f;
  for (int c = 0; c < 49; c++) {
    float a = As[c][hw];
#pragma unroll
    for (int j = 0; j < 16; j++) acc[j] = fmaf(wb[j * 49 + c], a, acc[j]);
  }
  int obase = (n * 64 + oc * 16) * 3136 + hw0 + hw;
#pragma unroll
  for (int j = 0; j < 16; j++) {
    int o = oc * 16 + j;
    int off = obase + j * 3136;
    O2[off] = fmaxf(fmaf(acc[j], g[o] * MSC_BNI, bb[o]) + R2[off], 0.f);
  }
}

// K6: 3x3 conv 64->64 (SAME) + BN + ReLU, + O2 -> C2 fp32.
// Block = (n, 2 output rows). Register-blocked window; LDS-staged epilogue.
__global__ __launch_bounds__(256) void k6_conv2(
    const float* R2, const float* O2, float* C2,
    const float* wcv, const float* g, const float* bb) {
  __shared__ float lds[64 * 4 * 58];            // 59,392 B; sIn then sOut
  int n = blockIdx.x / 28;
  int h0 = (blockIdx.x % 28) * 2;
  // stage input rows h0-1 .. h0+2 for all 64 channels
  for (int idx = threadIdx.x; idx < 14848; idx += 256) {
    int ch = idx / 232;
    int rem = idx - ch * 232;
    int r = rem / 58, cl = rem - r * 58;
    int gr = h0 - 1 + r, gc = cl - 1;
    float v = 0.f;
    if (gr >= 0 && gr < 56 && gc >= 0 && gc < 56)
      v = R2[(n * 64 + ch) * 3136 + gr * 56 + gc];
    lds[idx] = v;
  }
  __syncthreads();
  int o = threadIdx.x >> 2;                     // 0..63
  int w0 = (threadIdx.x & 3) * 14;              // col strip start
  float acc0[14], acc1[14];
#pragma unroll
  for (int j = 0; j < 14; j++) { acc0[j] = 0.f; acc1[j] = 0.f; }
  const float* wb = wcv + o * 576;
  for (int c = 0; c < 64; c++) {
    const float* w9 = wb + c * 9;
    float k00 = w9[0], k01 = w9[1], k02 = w9[2];
    float k10 = w9[3], k11 = w9[4], k12 = w9[5];
    float k20 = w9[6], k21 = w9[7], k22 = w9[8];
    const float* sc = lds + c * 232;
#pragma unroll
    for (int r = 0; r < 4; r++) {
      float v[16];
#pragma unroll
      for (int k = 0; k < 16; k++) v[k] = sc[r * 58 + w0 + k];
      if (r == 0) {
#pragma unroll
        for (int j = 0; j < 14; j++)
          acc0[j] = fmaf(k00, v[j], fmaf(k01, v[j+1], fmaf(k02, v[j+2], acc0[j])));
      } else if (r == 1) {
#pragma unroll
        for (int j = 0; j < 14; j++) {
          acc0[j] = fmaf(k10, v[j], fmaf(k11, v[j+1], fmaf(k12, v[j+2], acc0[j])));
          acc1[j] = fmaf(k00, v[j], fmaf(k01, v[j+1], fmaf(k02, v[j+2], acc1[j])));
        }
      } else if (r == 2) {
#pragma unroll
        for (int j = 0; j < 14; j++) {
          acc0[j] = fmaf(k20, v[j], fmaf(k21, v[j+1], fmaf(k22, v[j+2], acc0[j])));
          acc1[j] = fmaf(k10, v[j], fmaf(k11, v[j+1], fmaf(k12, v[j+2], acc1[j])));
        }
      } else {
#pragma unroll
        for (int j = 0; j < 14; j++)
          acc1[j] = fmaf(k20, v[j], fmaf(k21, v[j+1], fmaf(k22, v[j+2], acc1[j])));
      }
    }
  }
  __syncthreads();                              // sIn dead; reuse as sOut
  // sOut layout: row0 conv results at [o*56+col], row1 at [3584 + o*56+col]
#pragma unroll
  for (int j = 0; j < 14; j++) {
    lds[o * 56 + w0 + j] = acc0[j];
    lds[3584 + o * 56 + w0 + j] = acc1[j];
  }
  __syncthreads();
  // coalesced epilogue: BN + ReLU + O2-add, write C2
  for (int idx = threadIdx.x; idx < 7168; idx += 256) {
    int row = idx >> 11;                        // idx/3584? no: 7168/2=3584; use div
    int rem = idx - row * 3584;
    // careful: idx>>11 != idx/3584; compute properly:
    row = idx / 3584;
    rem = idx - row * 3584;
    int oo = rem / 56, col = rem - oo * 56;
    int off = (n * 64 + oo) * 3136 + (h0 + row) * 56 + col;
    float v = fmaxf(fmaf(lds[idx], g[oo] * MSC_BNI, bb[oo]), 0.f) + O2[off];
    C2[off] = v;
  }
}

// K7: 1x1 conv 64->256 + BN + x-residual + ReLU -> d_out FP32.
// Thread = one (n,hw) column; C2 channels in registers; fully coalesced.
__global__ __launch_bounds__(256) void k7_conv3(
    const float* C2, const float* x, float* outp,
    const float* w, const float* g, const float* bb) {
  int i = blockIdx.x * 256 + threadIdx.x;       // over NT*HW = 200,704
  int n = i / 3136;
  int hw = i - n * 3136;
  const float* Cb = C2 + n * 64 * 3136 + hw;
  float creg[64];
#pragma unroll
  for (int c = 0; c < 64; c++) creg[c] = Cb[c * 3136];
  const float* xb = x + n * 256 * 3136 + hw;
  float* ob = outp + n * 256 * 3136 + hw;
  for (int o = 0; o < 256; o++) {
    const float* wr = w + o * 64;               // wave-uniform -> s_loads
    float a0 = 0.f, a1 = 0.f, a2 = 0.f, a3 = 0.f;
#pragma unroll
    for (int c = 0; c < 16; c++) {
      a0 = fmaf(wr[4*c+0], creg[4*c+0], a0);
      a1 = fmaf(wr[4*c+1], creg[4*c+1], a1);
      a2 = fmaf(wr[4*c+2], creg[4*c+2], a2);
      a3 = fmaf(wr[4*c+3], creg[4*c+3], a3);
    }
    float acc = (a0 + a1) + (a2 + a3);
    float v = fmaxf(fmaf(acc, g[o] * MSC_BNI, bb[o]) + xb[o * 3136], 0.f);
    ob[o * 3136] = v;
  }
}

extern "C" void kernel_launch(void* const* d_in, const int* in_sizes, int n_in,
                              void* d_out, int out_size, void* d_ws, size_t ws_size,
                              hipStream_t stream) {
  const float* x        = (const float*)d_in[0];
  const float* w1       = (const float*)d_in[1];
  const float* w3       = (const float*)d_in[2];
  const float* w5       = (const float*)d_in[3];
  const float* w7       = (const float*)d_in[4];
  const float* w_conv1  = (const float*)d_in[5];
  const float* g1       = (const float*)d_in[6];
  const float* b1       = (const float*)d_in[7];
  const float* w_conv21 = (const float*)d_in[8];
  const float* g21      = (const float*)d_in[9];
  const float* b21      = (const float*)d_in[10];
  const float* g22      = (const float*)d_in[11];
  const float* b22      = (const float*)d_in[12];
  const float* w_conv22 = (const float*)d_in[13];
  const float* g23      = (const float*)d_in[14];
  const float* b23      = (const float*)d_in[15];
  const float* w_conv2  = (const float*)d_in[16];
  const float* g2       = (const float*)d_in[17];
  const float* b2       = (const float*)d_in[18];
  const float* w_conv3  = (const float*)d_in[19];
  const float* g3       = (const float*)d_in[20];
  const float* b3       = (const float*)d_in[21];

  // d_out (fp32, 205.5 MB) doubles as scratch for buffers dead before K7:
  //   A  bf16 [0 .. 102,760,448)           K1 w, K2 r
  //   Y  fp32 [0 .. 12,845,056)            K3 w, K4 r   (A dead)
  //   CO fp32 [12,845,056 .. 52,183,040)   K4 w, K5 r
  //   O2 fp32 [52,183,040 .. 103,563,264)  K5 w, K6 r
  //   out fp32 (all 205,520,896)           K7 w
  // d_ws: R2 fp32 [0 .. 51,380,224), C2 fp32 [51,380,224 .. 102,760,448)
  char* ob = (char*)d_out;
  char* ws = (char*)d_ws;
  unsigned short* A  = (unsigned short*)ob;
  float*          Yv = (float*)ob;
  float*          CO = (float*)(ob + 12845056);
  float*          O2 = (float*)(ob + 52183040);
  float*          R2 = (float*)ws;
  float*          C2 = (float*)(ws + 51380224);

  k1_tconv <<<dim3(25088),   dim3(256), 0, stream>>>(x, A, w1, w3, w5, w7);
  k2_conv1 <<<dim3(64 * 49), dim3(256), 0, stream>>>(A, R2, w_conv1, g1, b1);
  k3_conv21<<<dim3(64 * 49), dim3(256), 0, stream>>>(R2, Yv, w_conv21, g21, b21);
  k4_corr  <<<dim3(64 * 14), dim3(256), 0, stream>>>(Yv, CO, g22, b22);
  k5_conv22<<<dim3(64 * 49), dim3(256), 0, stream>>>(CO, R2, O2, w_conv22, g23, b23);
  k6_conv2 <<<dim3(64 * 28), dim3(256), 0, stream>>>(R2, O2, C2, w_conv2, g2, b2);
  k7_conv3 <<<dim3(784),     dim3(256), 0, stream>>>(C2, x, (float*)d_out, w_conv3, g3, b3);
}

// Round 8
// 1726.466 us; speedup vs baseline: 1.1124x; 1.1124x over previous
//
#include <hip/hip_runtime.h>

// MsCorrBlock: B=8 T=8 C=256 PL=64 CR=16 H=W=56 HW=3136 NT=64 PS=7 KK=49
// Output dtype: FLOAT32 (205,520,896 B). BNI = 1/sqrt(1+1e-5).

#define MSC_BNI 0.9999950000374997f

static __device__ __forceinline__ float b2f(unsigned short h) {
  return __uint_as_float(((unsigned int)h) << 16);
}
static __device__ __forceinline__ unsigned short f2b(float f) {
  unsigned int u = __float_as_uint(f);
  u = u + 0x7FFFu + ((u >> 16) & 1u);   // round to nearest even
  return (unsigned short)(u >> 16);
}

// K0: weight transposes.  Wt1[c][o] = w1[o][c] (256x64).  Wt2[i][o][k] = w2[o][i][k].
__global__ __launch_bounds__(256) void k0_prep(
    const float* w1, const float* w2, float* Wt1, float* Wt2) {
  int idx = blockIdx.x * 256 + threadIdx.x;
  if (idx < 16384) {
    int c = idx >> 6, o = idx & 63;
    Wt1[idx] = w1[o * 256 + c];
  } else if (idx < 16384 + 36864) {
    int j = idx - 16384;
    int i = j / 576;
    int r = j - i * 576;
    int o = r / 9, k = r - o * 9;
    Wt2[j] = w2[o * 576 + i * 9 + k];
  }
}

// K1: per-channel temporal conv (K=1/3/5/7 by channel quarter), x fp32 -> A bf16.
__global__ __launch_bounds__(256) void k1_tconv(
    const float* x, unsigned short* A,
    const float* w1, const float* w3, const float* w5, const float* w7) {
  int i = blockIdx.x * 256 + threadIdx.x;       // over 8*256*3136 = 6,422,528
  if (i >= 6422528) return;
  int hw = i % 3136;
  int bc = i / 3136;
  int c = bc & 255;
  int b = bc >> 8;
  int q = c >> 6, cc = c & 63;
  float wf[7];
#pragma unroll
  for (int k = 0; k < 7; k++) wf[k] = 0.f;
  if (q == 0) { wf[3] = w1[cc]; }
  else if (q == 1) { wf[2] = w3[cc*3]; wf[3] = w3[cc*3+1]; wf[4] = w3[cc*3+2]; }
  else if (q == 2) { wf[1] = w5[cc*5]; wf[2] = w5[cc*5+1]; wf[3] = w5[cc*5+2]; wf[4] = w5[cc*5+3]; wf[5] = w5[cc*5+4]; }
  else { wf[0] = w7[cc*7]; wf[1] = w7[cc*7+1]; wf[2] = w7[cc*7+2]; wf[3] = w7[cc*7+3]; wf[4] = w7[cc*7+4]; wf[5] = w7[cc*7+5]; wf[6] = w7[cc*7+6]; }

  int base = (b * 8 * 256 + c) * 3136 + hw;     // t=0 element
  int tstr = 256 * 3136;
  float xv[8];
#pragma unroll
  for (int t = 0; t < 8; t++) xv[t] = x[base + t * tstr];
#pragma unroll
  for (int t = 0; t < 8; t++) {
    float a = 0.f;
#pragma unroll
    for (int d = -3; d <= 3; d++) {
      int ts = t + d;
      if (ts >= 0 && ts < 8) a = fmaf(wf[d + 3], xv[ts], a);
    }
    A[base + t * tstr] = f2b(a);
  }
}

// K2: 1x1 conv 256->64 + BN + ReLU.  A bf16 -> R2 fp32.
// Thread = (n,hw) column: acc[64] in regs, stream c; weights Wt1[c][o]
// contiguous + wave-uniform (s_load); all global IO lane-coalesced.
__global__ __launch_bounds__(256) void k2_conv1(
    const unsigned short* A, float* R2,
    const float* Wt1, const float* g, const float* bb) {
  int i = blockIdx.x * 256 + threadIdx.x;       // over 200,704
  int n = i / 3136;
  int hw = i - n * 3136;
  const unsigned short* Ab = A + n * 256 * 3136 + hw;
  float acc[64];
#pragma unroll
  for (int o = 0; o < 64; o++) acc[o] = 0.f;
  for (int c = 0; c < 256; c++) {
    float a = b2f(Ab[c * 3136]);
    const float* wc = Wt1 + c * 64;             // wave-uniform, contiguous
#pragma unroll
    for (int o = 0; o < 64; o++) acc[o] = fmaf(wc[o], a, acc[o]);
  }
  float* Rb = R2 + n * 64 * 3136 + hw;
#pragma unroll
  for (int o = 0; o < 64; o++) {
    Rb[o * 3136] = fmaxf(fmaf(acc[o], g[o] * MSC_BNI, bb[o]), 0.f);
  }
}

// K3: 1x1 conv 64->16 + BN + ReLU.  R2 -> Y.  Column in registers.
__global__ __launch_bounds__(256) void k3_conv21(
    const float* R2, float* Y,
    const float* w, const float* g, const float* bb) {
  int i = blockIdx.x * 256 + threadIdx.x;       // over 200,704
  int n = i / 3136;
  int hw = i - n * 3136;
  const float* Rb = R2 + n * 64 * 3136 + hw;
  float creg[64];
#pragma unroll
  for (int c = 0; c < 64; c++) creg[c] = Rb[c * 3136];
  float* Yb = Y + n * 16 * 3136 + hw;
  for (int o = 0; o < 16; o++) {
    const float* wr = w + o * 64;               // uniform, contiguous
    float a0 = 0.f, a1 = 0.f, a2 = 0.f, a3 = 0.f;
#pragma unroll
    for (int c = 0; c < 16; c++) {
      a0 = fmaf(wr[4*c+0], creg[4*c+0], a0);
      a1 = fmaf(wr[4*c+1], creg[4*c+1], a1);
      a2 = fmaf(wr[4*c+2], creg[4*c+2], a2);
      a3 = fmaf(wr[4*c+3], creg[4*c+3], a3);
    }
    float acc = (a0 + a1) + (a2 + a3);
    Yb[o * 3136] = fmaxf(fmaf(acc, g[o] * MSC_BNI, bb[o]), 0.f);
  }
}

// K4: 7x7-displacement correlation (vs t+1 clamped frame) /16 + BN + ReLU.
// Y (NT,16,HW) -> CO (NT,49,HW).  LDS ~38.8 KB.
__global__ __launch_bounds__(256) void k4_corr(
    const float* Y, float* CO, const float* g, const float* bb) {
  __shared__ float sb[10][16][62];              // rows h0-3..h0+6, ch, cols -3..58
  int n = blockIdx.x / 14;
  int h0 = (blockIdx.x % 14) * 4;
  int t = n & 7;
  int n2 = (t < 7) ? n + 1 : n;
  const float* Yb = Y + n2 * 16 * 3136;
  for (int idx = threadIdx.x; idx < 9920; idx += 256) {
    int r = idx / 992;
    int rem = idx - r * 992;
    int ch = rem / 62;
    int cl = rem - ch * 62;
    int gr = h0 - 3 + r, gc = cl - 3;
    float v = 0.f;
    if (gr >= 0 && gr < 56 && gc >= 0 && gc < 56)
      v = Yb[ch * 3136 + gr * 56 + gc];
    sb[r][ch][cl] = v;
  }
  __syncthreads();
  int pos = threadIdx.x;
  if (pos < 224) {
    int hl = pos / 56, wcol = pos - (pos / 56) * 56;
    float a[16];
    const float* Ya = Y + n * 16 * 3136 + (h0 + hl) * 56 + wcol;
#pragma unroll
    for (int c = 0; c < 16; c++) a[c] = Ya[c * 3136];
    float* Cp = CO + n * 49 * 3136 + (h0 + hl) * 56 + wcol;
    for (int di = 0; di < 7; di++) {
      for (int dj = 0; dj < 7; dj++) {
        float s = 0.f;
#pragma unroll
        for (int c = 0; c < 16; c++) s = fmaf(a[c], sb[hl + di][c][wcol + dj], s);
        int k = di * 7 + dj;
        float v = fmaf(s * 0.0625f, g[k] * MSC_BNI, bb[k]);
        Cp[k * 3136] = fmaxf(v, 0.f);
      }
    }
  }
}

// K6 (fused with K5): 3x3 conv 64->64 + BN + ReLU  +  O2 recomputed in-register
// from (CO, R2) via 1x1 conv 49->64 + BN + add + ReLU.  -> C2 fp32.
// Thread = (n,hw) column; acc[64]; Wt2[c][o][9] uniform contiguous.
__global__ __launch_bounds__(256) void k6_conv2(
    const float* R2, const float* CO, float* C2, const float* Wt2,
    const float* w22, const float* g23, const float* b23,
    const float* g2, const float* b2) {
  int i = blockIdx.x * 256 + threadIdx.x;       // over 200,704
  int n = i / 3136;
  int hw = i - n * 3136;
  int h = hw / 56, wq = hw - h * 56;
  bool hm = h > 0, hp = h < 55, wm = wq > 0, wp = wq < 55;
  float acc[64];
#pragma unroll
  for (int o = 0; o < 64; o++) acc[o] = 0.f;
  const float* Rn = R2 + n * 64 * 3136 + hw;
#pragma unroll 1
  for (int c = 0; c < 64; c++) {
    const float* pc = Rn + c * 3136;
    float v0 = (hm && wm) ? pc[-57] : 0.f;
    float v1 = hm         ? pc[-56] : 0.f;
    float v2 = (hm && wp) ? pc[-55] : 0.f;
    float v3 = wm         ? pc[-1]  : 0.f;
    float v4 =              pc[0];
    float v5 = wp         ? pc[1]   : 0.f;
    float v6 = (hp && wm) ? pc[55]  : 0.f;
    float v7 = hp         ? pc[56]  : 0.f;
    float v8 = (hp && wp) ? pc[57]  : 0.f;
    const float* wc = Wt2 + c * 576;            // uniform, contiguous
#pragma unroll
    for (int o = 0; o < 64; o++) {
      const float* w9 = wc + o * 9;
      float s = fmaf(w9[0], v0, fmaf(w9[1], v1, w9[2] * v2));
      s = fmaf(w9[3], v3, fmaf(w9[4], v4, fmaf(w9[5], v5, s)));
      s = fmaf(w9[6], v6, fmaf(w9[7], v7, fmaf(w9[8], v8, s)));
      acc[o] += s;
    }
  }
  // fused K5: O2[o] = relu(bn23(sum_c w22[o,c]*CO[c]) + R2[o])
  float co[49];
  const float* pco = CO + n * 49 * 3136 + hw;
#pragma unroll
  for (int c = 0; c < 49; c++) co[c] = pco[c * 3136];
  float* Cb = C2 + n * 64 * 3136 + hw;
  for (int o = 0; o < 64; o++) {
    const float* wr = w22 + o * 49;             // uniform, contiguous
    float s = 0.f;
#pragma unroll
    for (int c = 0; c < 49; c++) s = fmaf(wr[c], co[c], s);
    float o2 = fmaxf(fmaf(s, g23[o] * MSC_BNI, b23[o]) + Rn[o * 3136], 0.f);
    float v = fmaxf(fmaf(acc[o], g2[o] * MSC_BNI, b2[o]), 0.f) + o2;
    Cb[o * 3136] = v;
  }
}

// K7: 1x1 conv 64->256 + BN + x-residual + ReLU -> d_out FP32.
__global__ __launch_bounds__(256) void k7_conv3(
    const float* C2, const float* x, float* outp,
    const float* w, const float* g, const float* bb) {
  int i = blockIdx.x * 256 + threadIdx.x;       // over 200,704
  int n = i / 3136;
  int hw = i - n * 3136;
  const float* Cb = C2 + n * 64 * 3136 + hw;
  float creg[64];
#pragma unroll
  for (int c = 0; c < 64; c++) creg[c] = Cb[c * 3136];
  const float* xb = x + n * 256 * 3136 + hw;
  float* ob = outp + n * 256 * 3136 + hw;
  for (int o = 0; o < 256; o++) {
    const float* wr = w + o * 64;               // uniform, contiguous
    float a0 = 0.f, a1 = 0.f, a2 = 0.f, a3 = 0.f;
#pragma unroll
    for (int c = 0; c < 16; c++) {
      a0 = fmaf(wr[4*c+0], creg[4*c+0], a0);
      a1 = fmaf(wr[4*c+1], creg[4*c+1], a1);
      a2 = fmaf(wr[4*c+2], creg[4*c+2], a2);
      a3 = fmaf(wr[4*c+3], creg[4*c+3], a3);
    }
    float acc = (a0 + a1) + (a2 + a3);
    float v = fmaxf(fmaf(acc, g[o] * MSC_BNI, bb[o]) + xb[o * 3136], 0.f);
    ob[o * 3136] = v;
  }
}

extern "C" void kernel_launch(void* const* d_in, const int* in_sizes, int n_in,
                              void* d_out, int out_size, void* d_ws, size_t ws_size,
                              hipStream_t stream) {
  const float* x        = (const float*)d_in[0];
  const float* w1       = (const float*)d_in[1];
  const float* w3       = (const float*)d_in[2];
  const float* w5       = (const float*)d_in[3];
  const float* w7       = (const float*)d_in[4];
  const float* w_conv1  = (const float*)d_in[5];
  const float* g1       = (const float*)d_in[6];
  const float* b1       = (const float*)d_in[7];
  const float* w_conv21 = (const float*)d_in[8];
  const float* g21      = (const float*)d_in[9];
  const float* b21      = (const float*)d_in[10];
  const float* g22      = (const float*)d_in[11];
  const float* b22      = (const float*)d_in[12];
  const float* w_conv22 = (const float*)d_in[13];
  const float* g23      = (const float*)d_in[14];
  const float* b23      = (const float*)d_in[15];
  const float* w_conv2  = (const float*)d_in[16];
  const float* g2       = (const float*)d_in[17];
  const float* b2       = (const float*)d_in[18];
  const float* w_conv3  = (const float*)d_in[19];
  const float* g3       = (const float*)d_in[20];
  const float* b3       = (const float*)d_in[21];

  // d_out (fp32, 205.5 MB) doubles as scratch:
  //   A   bf16 [0 .. 102,760,448)            K1 w, K2 r
  //   Y   fp32 [0 .. 12,845,056)             K3 w, K4 r   (A dead)
  //   CO  fp32 [12,845,056 .. 52,183,040)    K4 w, K6 r
  //   Wt1 fp32 [110,100,480 .. +65,536)      K0 w, K2 r
  //   Wt2 fp32 [110,166,016 .. +147,456)     K0 w, K6 r
  //   out fp32 (all)                         K7 w (everything above dead)
  // d_ws: R2 fp32 [0 .. 51,380,224), C2 fp32 [51,380,224 .. 102,760,448)
  char* ob = (char*)d_out;
  char* ws = (char*)d_ws;
  unsigned short* A   = (unsigned short*)ob;
  float*          Yv  = (float*)ob;
  float*          CO  = (float*)(ob + 12845056);
  float*          Wt1 = (float*)(ob + 110100480);
  float*          Wt2 = (float*)(ob + 110166016);
  float*          R2  = (float*)ws;
  float*          C2  = (float*)(ws + 51380224);

  k0_prep  <<<dim3(208),     dim3(256), 0, stream>>>(w_conv1, w_conv2, Wt1, Wt2);
  k1_tconv <<<dim3(25088),   dim3(256), 0, stream>>>(x, A, w1, w3, w5, w7);
  k2_conv1 <<<dim3(784),     dim3(256), 0, stream>>>(A, R2, Wt1, g1, b1);
  k3_conv21<<<dim3(784),     dim3(256), 0, stream>>>(R2, Yv, w_conv21, g21, b21);
  k4_corr  <<<dim3(64 * 14), dim3(256), 0, stream>>>(Yv, CO, g22, b22);
  k6_conv2 <<<dim3(784),     dim3(256), 0, stream>>>(R2, CO, C2, Wt2, w_conv22, g23, b23, g2, b2);
  k7_conv3 <<<dim3(784),     dim3(256), 0, stream>>>(C2, x, (float*)d_out, w_conv3, g3, b3);
}